// Round 4
// baseline (232.848 us; speedup 1.0000x reference)
//
#include <hip/hip_runtime.h>
#include <hip/hip_bf16.h>

#define N_ROWS 10000
#define F_DIM 256
#define J4 2500                      // float4 per row
#define TOTAL_F4 25000000            // N_ROWS * J4
#define LOG2E 1.44269504088896340736f
#define REPS 4                       // DIAGNOSTIC: rewrite identical output 4x
                                     // to push this dispatch into rocprof top-5

typedef float f32x4 __attribute__((ext_vector_type(4)));

// Kernel 1: per-row dot products -> e1[i] = exp(-(x@w1 + b)), e2[j] = exp(-(x@w2)).
__global__ void dot_kernel(const float* __restrict__ x,
                           const float* __restrict__ w,
                           const float* __restrict__ b,
                           float* __restrict__ e1,
                           float* __restrict__ e2) {
    const int wid  = threadIdx.x >> 6;          // wave 0..3
    const int lane = threadIdx.x & 63;
    const int row  = blockIdx.x * 4 + wid;
    const f32x4 xv = reinterpret_cast<const f32x4*>(x + (size_t)row * F_DIM)[lane];
    const f32x4 w1 = reinterpret_cast<const f32x4*>(w)[lane];
    const f32x4 w2 = reinterpret_cast<const f32x4*>(w + F_DIM)[lane];
    float p1 = xv.x * w1.x + xv.y * w1.y + xv.z * w1.z + xv.w * w1.w;
    float p2 = xv.x * w2.x + xv.y * w2.y + xv.z * w2.z + xv.w * w2.w;
    #pragma unroll
    for (int o = 32; o > 0; o >>= 1) {
        p1 += __shfl_xor(p1, o);
        p2 += __shfl_xor(p2, o);
    }
    if (lane == 0) {
        e1[row] = __builtin_amdgcn_exp2f(-(p1 + b[0]) * LOG2E);
        e2[row] = __builtin_amdgcn_exp2f(-p2 * LOG2E);
    }
}

// Kernel 2 (DIAGNOSTIC x4): out[i][j] = 1 / (1 + e1[i]*e2[j]).
// Identical work repeated REPS times so the dispatch exceeds the harness
// fillBuffer duration and its counters appear in the rocprof top-5.
__global__ void att_kernel(const float* __restrict__ e1,
                           const float* __restrict__ e2,
                           float* __restrict__ out) {
    const unsigned stride = gridDim.x * blockDim.x;
    f32x4* __restrict__ o4 = reinterpret_cast<f32x4*>(out);
    for (int rep = 0; rep < REPS; ++rep) {
        for (unsigned idx = blockIdx.x * blockDim.x + threadIdx.x;
             idx < TOTAL_F4; idx += stride) {
            const unsigned i   = idx / 2500u;        // magic-mul
            const unsigned rem = idx - i * 2500u;
            const float a = e1[i];
            const f32x4 ev = reinterpret_cast<const f32x4*>(e2)[rem];
            f32x4 o;
            o.x = __builtin_amdgcn_rcpf(fmaf(a, ev.x, 1.0f));
            o.y = __builtin_amdgcn_rcpf(fmaf(a, ev.y, 1.0f));
            o.z = __builtin_amdgcn_rcpf(fmaf(a, ev.z, 1.0f));
            o.w = __builtin_amdgcn_rcpf(fmaf(a, ev.w, 1.0f));
            o4[idx] = o;
        }
        // prevent dead-store elimination of earlier passes
        asm volatile("" ::: "memory");
    }
}

extern "C" void kernel_launch(void* const* d_in, const int* in_sizes, int n_in,
                              void* d_out, int out_size, void* d_ws, size_t ws_size,
                              hipStream_t stream) {
    const float* x = (const float*)d_in[0];
    // d_in[1] = adj (unused by the reference output)
    const float* w = (const float*)d_in[2];
    const float* b = (const float*)d_in[3];
    float* out = (float*)d_out;

    float* e1 = (float*)d_ws;               // N_ROWS floats
    float* e2 = e1 + N_ROWS;                // N_ROWS floats

    dot_kernel<<<N_ROWS / 4, 256, 0, stream>>>(x, w, b, e1, e2);

    att_kernel<<<4096, 256, 0, stream>>>(e1, e2, out);
}

// Round 6
// 90.641 us; speedup vs baseline: 2.5689x; 2.5689x over previous
//
#include <hip/hip_runtime.h>
#include <hip/hip_bf16.h>

#define N_ROWS 10000
#define F_DIM 256
#define J4 2500u                     // float4 per row
#define NBANDS 200u                  // row bands
#define ROWS_PER_BAND 50u            // 10000 / 200
#define NTHREADS (J4 * NBANDS)       // 500000 worker threads
#define NBLK 1954                    // ceil(500000/256); 7816 waves <= 8192 resident
#define LOG2E 1.44269504088896340736f

typedef float f32x4 __attribute__((ext_vector_type(4)));

// Kernel 1: per-row dot products -> e1[i] = exp(-(x@w1 + b)), e2[j] = exp(-(x@w2)).
__global__ void dot_kernel(const float* __restrict__ x,
                           const float* __restrict__ w,
                           const float* __restrict__ b,
                           float* __restrict__ e1,
                           float* __restrict__ e2) {
    const int wid  = threadIdx.x >> 6;          // wave 0..3
    const int lane = threadIdx.x & 63;
    const int row  = blockIdx.x * 4 + wid;
    const f32x4 xv = reinterpret_cast<const f32x4*>(x + (size_t)row * F_DIM)[lane];
    const f32x4 w1 = reinterpret_cast<const f32x4*>(w)[lane];
    const f32x4 w2 = reinterpret_cast<const f32x4*>(w + F_DIM)[lane];
    float p1 = xv.x * w1.x + xv.y * w1.y + xv.z * w1.z + xv.w * w1.w;
    float p2 = xv.x * w2.x + xv.y * w2.y + xv.z * w2.z + xv.w * w2.w;
    #pragma unroll
    for (int o = 32; o > 0; o >>= 1) {
        p1 += __shfl_xor(p1, o);
        p2 += __shfl_xor(p2, o);
    }
    if (lane == 0) {
        e1[row] = __builtin_amdgcn_exp2f(-(p1 + b[0]) * LOG2E);
        e2[row] = __builtin_amdgcn_exp2f(-p2 * LOG2E);
    }
}

// Kernel 2: out[i][j] = 1 / (1 + e1[i]*e2[j]).
// Column-band decomposition: each thread owns one float4 of e2 (register-
// resident) and sweeps ROWS_PER_BAND rows. Grid-wide e2 read traffic: 40 KB
// total. Per iteration: one wave-uniform e1 load (L1 hit) + 1 KB/wave
// contiguous store.
__global__ void att_kernel(const float* __restrict__ e1,
                           const float* __restrict__ e2,
                           float* __restrict__ out) {
    const unsigned tid = blockIdx.x * 256u + threadIdx.x;
    if (tid >= NTHREADS) return;
    const unsigned band = tid / J4;              // 0..199 (magic-mul)
    const unsigned j4   = tid - band * J4;       // 0..2499
    const f32x4 ev = reinterpret_cast<const f32x4*>(e2)[j4];
    f32x4* __restrict__ o4 = reinterpret_cast<f32x4*>(out) + (size_t)band * ROWS_PER_BAND * J4 + j4;
    const float* __restrict__ e1p = e1 + band * ROWS_PER_BAND;

    #pragma unroll 2
    for (unsigned r = 0; r < ROWS_PER_BAND; ++r) {
        const float a = e1p[r];
        f32x4 o;
        o.x = __builtin_amdgcn_rcpf(fmaf(a, ev.x, 1.0f));
        o.y = __builtin_amdgcn_rcpf(fmaf(a, ev.y, 1.0f));
        o.z = __builtin_amdgcn_rcpf(fmaf(a, ev.z, 1.0f));
        o.w = __builtin_amdgcn_rcpf(fmaf(a, ev.w, 1.0f));
        o4[(size_t)r * J4] = o;
    }
}

extern "C" void kernel_launch(void* const* d_in, const int* in_sizes, int n_in,
                              void* d_out, int out_size, void* d_ws, size_t ws_size,
                              hipStream_t stream) {
    const float* x = (const float*)d_in[0];
    // d_in[1] = adj (unused by the reference output)
    const float* w = (const float*)d_in[2];
    const float* b = (const float*)d_in[3];
    float* out = (float*)d_out;

    float* e1 = (float*)d_ws;               // N_ROWS floats
    float* e2 = e1 + N_ROWS;                // N_ROWS floats

    dot_kernel<<<N_ROWS / 4, 256, 0, stream>>>(x, w, b, e1, e2);

    att_kernel<<<NBLK, 256, 0, stream>>>(e1, e2, out);
}

// Round 7
// 85.628 us; speedup vs baseline: 2.7193x; 1.0585x over previous
//
#include <hip/hip_runtime.h>
#include <hip/hip_bf16.h>

#define N_ROWS 10000
#define F_DIM 256
#define J4 2500u                     // float4 per row
#define RPT 8u                       // rows per thread
#define NBANDY (N_ROWS / RPT)        // 1250 bands
#define LOG2E 1.44269504088896340736f

typedef float f32x4 __attribute__((ext_vector_type(4)));

// Kernel 1: per-row dot products -> e1[i] = exp(-(x@w1 + b)), e2[j] = exp(-(x@w2)).
__global__ void dot_kernel(const float* __restrict__ x,
                           const float* __restrict__ w,
                           const float* __restrict__ b,
                           float* __restrict__ e1,
                           float* __restrict__ e2) {
    const int wid  = threadIdx.x >> 6;          // wave 0..3
    const int lane = threadIdx.x & 63;
    const int row  = blockIdx.x * 4 + wid;
    const f32x4 xv = reinterpret_cast<const f32x4*>(x + (size_t)row * F_DIM)[lane];
    const f32x4 w1 = reinterpret_cast<const f32x4*>(w)[lane];
    const f32x4 w2 = reinterpret_cast<const f32x4*>(w + F_DIM)[lane];
    float p1 = xv.x * w1.x + xv.y * w1.y + xv.z * w1.z + xv.w * w1.w;
    float p2 = xv.x * w2.x + xv.y * w2.y + xv.z * w2.z + xv.w * w2.w;
    #pragma unroll
    for (int o = 32; o > 0; o >>= 1) {
        p1 += __shfl_xor(p1, o);
        p2 += __shfl_xor(p2, o);
    }
    if (lane == 0) {
        e1[row] = __builtin_amdgcn_exp2f(-(p1 + b[0]) * LOG2E);
        e2[row] = __builtin_amdgcn_exp2f(-p2 * LOG2E);
    }
}

// Kernel 2: out[i][j] = 1 / (1 + e1[i]*e2[j]).
// 2D grid: x tiles columns (one float4 of e2 per thread, register-resident),
// y tiles 8-row bands. Nontemporal float4 stores (bypass L2 write-allocate).
__global__ void att_kernel(const float* __restrict__ e1,
                           const float* __restrict__ e2,
                           float* __restrict__ out) {
    const unsigned j4 = blockIdx.x * 256u + threadIdx.x;
    if (j4 >= J4) return;
    const unsigned i0 = blockIdx.y * RPT;
    const f32x4 ev = reinterpret_cast<const f32x4*>(e2)[j4];
    f32x4* __restrict__ o4 = reinterpret_cast<f32x4*>(out) + (size_t)i0 * J4 + j4;

    #pragma unroll
    for (unsigned r = 0; r < RPT; ++r) {
        const float a = e1[i0 + r];
        f32x4 o;
        o.x = __builtin_amdgcn_rcpf(fmaf(a, ev.x, 1.0f));
        o.y = __builtin_amdgcn_rcpf(fmaf(a, ev.y, 1.0f));
        o.z = __builtin_amdgcn_rcpf(fmaf(a, ev.z, 1.0f));
        o.w = __builtin_amdgcn_rcpf(fmaf(a, ev.w, 1.0f));
        __builtin_nontemporal_store(o, o4 + (size_t)r * J4);
    }
}

extern "C" void kernel_launch(void* const* d_in, const int* in_sizes, int n_in,
                              void* d_out, int out_size, void* d_ws, size_t ws_size,
                              hipStream_t stream) {
    const float* x = (const float*)d_in[0];
    // d_in[1] = adj (unused by the reference output)
    const float* w = (const float*)d_in[2];
    const float* b = (const float*)d_in[3];
    float* out = (float*)d_out;

    float* e1 = (float*)d_ws;               // N_ROWS floats
    float* e2 = e1 + N_ROWS;                // N_ROWS floats

    dot_kernel<<<N_ROWS / 4, 256, 0, stream>>>(x, w, b, e1, e2);

    dim3 grid((J4 + 255u) / 256u, NBANDY);
    att_kernel<<<grid, 256, 0, stream>>>(e1, e2, out);
}

// Round 8
// 82.487 us; speedup vs baseline: 2.8228x; 1.0381x over previous
//
#include <hip/hip_runtime.h>
#include <hip/hip_bf16.h>

#define N_ROWS 10000
#define F_DIM 256
#define J4 (N_ROWS / 4)   // 2500 float4 per row
#define LOG2E 1.44269504088896340736f

typedef float f32x4 __attribute__((ext_vector_type(4)));

// Kernel 1: per-row dot products -> e1[i] = exp(-(x@w1 + b)), e2[j] = exp(-(x@w2)).
// 4 waves per block, one row per wave, float4 loads.
__global__ void dot_kernel(const float* __restrict__ x,
                           const float* __restrict__ w,
                           const float* __restrict__ b,
                           float* __restrict__ e1,
                           float* __restrict__ e2) {
    const int wid  = threadIdx.x >> 6;          // wave 0..3
    const int lane = threadIdx.x & 63;
    const int row  = blockIdx.x * 4 + wid;
    const f32x4 xv = reinterpret_cast<const f32x4*>(x + (size_t)row * F_DIM)[lane];
    const f32x4 w1 = reinterpret_cast<const f32x4*>(w)[lane];
    const f32x4 w2 = reinterpret_cast<const f32x4*>(w + F_DIM)[lane];
    float p1 = xv.x * w1.x + xv.y * w1.y + xv.z * w1.z + xv.w * w1.w;
    float p2 = xv.x * w2.x + xv.y * w2.y + xv.z * w2.z + xv.w * w2.w;
    #pragma unroll
    for (int o = 32; o > 0; o >>= 1) {
        p1 += __shfl_xor(p1, o);
        p2 += __shfl_xor(p2, o);
    }
    if (lane == 0) {
        e1[row] = __builtin_amdgcn_exp2f(-(p1 + b[0]) * LOG2E);
        e2[row] = __builtin_amdgcn_exp2f(-p2 * LOG2E);
    }
}

// Kernel 2: out[i][j] = 1 / (1 + e1[i]*e2[j]).
// Each thread: one float4 of e2 (register-resident), 4 consecutive rows ->
// 4 nontemporal float4 stores (bypass L2 write-allocate on the 400 MB stream).
__global__ void att_kernel(const float* __restrict__ e1,
                           const float* __restrict__ e2,
                           float* __restrict__ out) {
    const int j4 = blockIdx.x * blockDim.x + threadIdx.x;   // 0..J4-1
    if (j4 >= J4) return;
    const int i0 = blockIdx.y * 4;
    const f32x4 ev = reinterpret_cast<const f32x4*>(e2)[j4];
    #pragma unroll
    for (int r = 0; r < 4; ++r) {
        const float a = e1[i0 + r];
        f32x4 o;
        o.x = __builtin_amdgcn_rcpf(fmaf(a, ev.x, 1.0f));
        o.y = __builtin_amdgcn_rcpf(fmaf(a, ev.y, 1.0f));
        o.z = __builtin_amdgcn_rcpf(fmaf(a, ev.z, 1.0f));
        o.w = __builtin_amdgcn_rcpf(fmaf(a, ev.w, 1.0f));
        __builtin_nontemporal_store(
            o, reinterpret_cast<f32x4*>(out) + (size_t)(i0 + r) * J4 + j4);
    }
}

extern "C" void kernel_launch(void* const* d_in, const int* in_sizes, int n_in,
                              void* d_out, int out_size, void* d_ws, size_t ws_size,
                              hipStream_t stream) {
    const float* x = (const float*)d_in[0];
    // d_in[1] = adj (unused by the reference output)
    const float* w = (const float*)d_in[2];
    const float* b = (const float*)d_in[3];
    float* out = (float*)d_out;

    float* e1 = (float*)d_ws;               // N_ROWS floats
    float* e2 = e1 + N_ROWS;                // N_ROWS floats

    dot_kernel<<<N_ROWS / 4, 256, 0, stream>>>(x, w, b, e1, e2);

    dim3 grid((J4 + 255) / 256, N_ROWS / 4);
    att_kernel<<<grid, 256, 0, stream>>>(e1, e2, out);
}